// Round 4
// baseline (214.630 us; speedup 1.0000x reference)
//
#include <hip/hip_runtime.h>
#include <hip/hip_fp16.h>
#include <cstdint>
#include <cstddef>

#define T_DIM 5
#define F_DIM 8
#define Z_DIM 16
#define Y_DIM 96
#define X_DIM 96
#define NRAYS 32768
#define K_SAMP 128

// Pipeline:
//   prep_w    : wB f16 [p=ci/32][tap 27][zo 16][ci32]  + bR f32[16] + loU/hiU init
//   transpose : inp f16 [t][y][x][ci=f*16+z]
//   nearfar   : unchanged
//   conv_mfma : fld f32 [t][zo][y][x] via v_mfma_f32_16x16x32_f16
//               LDS double-buffer, reg-staged async prefetch, 1 barrier/phase
//   pack      : fld -> cellp, cells stored as (lo, hi-lo) half2 pairs
//   render    : grid-space march, log2-domain optics, 1-iter cell prefetch pipeline

struct __align__(16) Cell { __half2 h0, h1, h2, h3; };

typedef __attribute__((ext_vector_type(4))) float     f32x4;
typedef __attribute__((ext_vector_type(8))) _Float16  f16x8;

__device__ __forceinline__ float fexp2(float x) { return __builtin_amdgcn_exp2f(x); }   // v_exp_f32
__device__ __forceinline__ float flog2(float x) { return __builtin_amdgcn_logf(x); }    // v_log_f32

__global__ __launch_bounds__(256) void prep_w_kernel(
        const float* __restrict__ w, const float* __restrict__ cb,
        const float* __restrict__ dw,
        __half* __restrict__ wB, float* __restrict__ bR,
        unsigned* loU, unsigned* hiU) {
    int i = blockIdx.x * 256 + threadIdx.x;          // 0 .. 55295 exactly
    if (i < 8) { loU[i] = 0x7F800000u; hiU[i] = 0u; }
    if (i < 16) {
        float s = 0.f;
        #pragma unroll
        for (int f = 0; f < 8; ++f) s += cb[f * 16 + i] * dw[f];
        bR[i] = s;
    }
    int cs  = i & 31;
    int zo  = (i >> 5) & 15;
    int pt  = i >> 9;            // p*27 + tap, 0..107
    int p   = pt / 27;
    int tap = pt - p * 27;
    int ci  = p * 32 + cs;
    float s = 0.f;
    #pragma unroll
    for (int f = 0; f < 8; ++f)
        s += w[(size_t)((f * 16 + zo) * 128 + ci) * 27 + tap] * dw[f];
    wB[i] = __float2half(s);
}

// inp[((t*96+y)*96+x)*128 + f*16+z] = (half) vol[f][t][z][y][x]
__global__ __launch_bounds__(256) void transpose_vol_kernel(
        const float* __restrict__ xin, __half* __restrict__ inp) {
    __shared__ __half lds[96 * 136];
    int b = blockIdx.x;                              // 480 = 5*96
    int t = b / 96, y = b - (b / 96) * 96;
    for (int i = threadIdx.x; i < 12288; i += 256) {
        int row = i / 96;
        int x   = i - row * 96;
        int f = row >> 4, z = row & 15;
        float v = xin[(((size_t)(f * 5 + t) * 16 + z) * 96 + y) * 96 + x];
        lds[x * 136 + row] = __float2half(v);
    }
    __syncthreads();
    __half* ob = inp + ((size_t)(t * 96 + y) * 96) * 128;
    for (int c = threadIdx.x; c < 1536; c += 256) {
        int x = c >> 4, sub = c & 15;
        uint4 v = *(const uint4*)(lds + x * 136 + sub * 8);
        *(uint4*)(ob + (size_t)x * 128 + sub * 8) = v;
    }
}

__global__ __launch_bounds__(256) void nearfar_kernel(
        const float* __restrict__ ro, const float* __restrict__ rd,
        float* __restrict__ nearA, float* __restrict__ farA,
        unsigned* loU, unsigned* hiU) {
    int gid = blockIdx.x * 256 + threadIdx.x;
    int t = gid / NRAYS;
    const float* o = ro + (size_t)gid * 3;
    const float* d = rd + (size_t)gid * 3;
    float ox = o[0], oy = o[1], oz = o[2];
    float dx = d[0], dy = d[1], dz = d[2];
    float t1x = (0.f - ox) / dx, t2x = (1.f - ox) / dx;
    float t1y = (0.f - oy) / dy, t2y = (1.f - oy) / dy;
    float t1z = (0.f - oz) / dz, t2z = (1.f - oz) / dz;
    float nr = fmaxf(fmaxf(fminf(t1x, t2x), fminf(t1y, t2y)), fminf(t1z, t2z));
    float fr = fminf(fminf(fmaxf(t1x, t2x), fmaxf(t1y, t2y)), fmaxf(t1z, t2z));
    nr = fmaxf(nr, 0.01f);
    fr = fmaxf(fr, nr + 1e-6f);
    nearA[gid] = nr;
    farA[gid]  = fr;
    float slast = fmaf(0.9921875f, fr - nr, nr);
    float mn = nr, mx = slast;
    #pragma unroll
    for (int off = 32; off > 0; off >>= 1) {
        mn = fminf(mn, __shfl_down(mn, off, 64));
        mx = fmaxf(mx, __shfl_down(mx, off, 64));
    }
    __shared__ float smn[4], smx[4];
    int w = threadIdx.x >> 6;
    if ((threadIdx.x & 63) == 0) { smn[w] = mn; smx[w] = mx; }
    __syncthreads();
    if (threadIdx.x == 0) {
        mn = fminf(fminf(smn[0], smn[1]), fminf(smn[2], smn[3]));
        mx = fmaxf(fmaxf(smx[0], smx[1]), fmaxf(smx[2], smx[3]));
        atomicMin(&loU[t], __float_as_uint(mn));
        atomicMax(&hiU[t], __float_as_uint(mx));
    }
}

// Block = (t, y-pair, 32-x seg), 128 thr (2 waves; wave w -> y = y0+w, two 16-x tiles).
// LDS: 2 buffers of [12 rows][34 x][4 slots of 8 halves], slot s' = sub ^ ((xl>>1)&3).
// Phase p: ds_write(buf[p&1]) -> barrier -> issue global loads(p+1) -> compute(buf[p&1]).
// Buffer safety: per-wave order C(p-1) < A(p) < B(p); so at barrier B(p) every wave has
// finished reading buf[(p+1)&1] (= buf[(p-1)&1]); A(p+1) writes it only after B(p). One
// barrier per phase; staging loads ride under the previous phase's MFMA/ds work.
__global__ __launch_bounds__(128) void conv_mfma_kernel(
        const __half* __restrict__ inp, const __half* __restrict__ wB,
        const float* __restrict__ bR, float* __restrict__ fld) {
    int bid = blockIdx.x;
    int wg  = (bid & 7) * 90 + (bid >> 3);     // bijective XCD swizzle (720 = 8*90)
    int xs  = wg % 3;
    int rem = wg / 3;
    int yp  = rem % 48;
    int t   = rem / 48;
    int xseg = xs * 32, y0 = yp * 2;

    __shared__ __half lds[2][12 * 34 * 32];          // 2 x 26,112 B
    const int w    = threadIdx.x >> 6;
    const int lane = threadIdx.x & 63;
    const int l15  = lane & 15;
    const int ksub = lane >> 4;

    // ---- main staging columns: 128 lanes x 12 rows (xl 0..31, sub 0..3) ----
    const int xl0 = threadIdx.x >> 2, sub0 = threadIdx.x & 3;
    const int xg0 = xseg + xl0 - 1;
    const bool xok0 = (unsigned)xg0 < 96u;
    const int glo0 = xg0 * 128 + sub0 * 8;                       // halves (+p*32 later)
    const int lof0 = xl0 * 32 + ((sub0 ^ ((xl0 >> 1) & 3)) << 3);
    // ---- halo: 96 chunks (xl 32..33, sub 0..3, rows 0..11) -> lanes 0..95, 1 each ----
    const int q    = threadIdx.x / 12;                           // 0..10
    const int rowh = threadIdx.x - q * 12;                       // 0..11
    const int xl1  = 32 + (q >> 2), sub1 = q & 3;
    const int xg1  = xseg + xl1 - 1;
    const bool hwr = (q < 8);                                    // has a halo slot
    const bool hld = hwr && ((unsigned)xg1 < 96u);
    const int glo1 = xg1 * 128 + sub1 * 8;
    const int lof1 = xl1 * 32 + ((sub1 ^ ((xl1 >> 1) & 3)) << 3);

    // ---- swizzled B-fragment read offsets (halves) ----
    int offA[3];
    #pragma unroll
    for (int kx = 0; kx < 3; ++kx) {
        int X = l15 + kx;
        offA[kx] = X * 32 + ((ksub ^ ((X >> 1) & 3)) << 3);      // tile B = +512
    }

    uint4 vm[12];
    uint4 vh;
    f32x4 acc0 = {0.f, 0.f, 0.f, 0.f};
    f32x4 acc1 = {0.f, 0.f, 0.f, 0.f};

    // ---- prologue: issue loads for p=0 ----
    #pragma unroll
    for (int r = 0; r < 12; ++r) {
        int tt = t + (r >> 2) - 1;
        int yy = y0 + (r & 3) - 1;
        bool rok = ((unsigned)tt < 5u) & ((unsigned)yy < 96u);
        int rbase = (tt * 96 + yy) * 12288;
        uint4 v = {0u, 0u, 0u, 0u};
        if (rok & xok0) v = *(const uint4*)(inp + rbase + glo0);
        vm[r] = v;
    }
    {
        int tt = t + (rowh >> 2) - 1;
        int yy = y0 + (rowh & 3) - 1;
        bool rok = ((unsigned)tt < 5u) & ((unsigned)yy < 96u);
        int rbase = (tt * 96 + yy) * 12288;
        uint4 v = {0u, 0u, 0u, 0u};
        if (rok & hld) v = *(const uint4*)(inp + rbase + glo1);
        vh = v;
    }

    #pragma unroll
    for (int p = 0; p < 4; ++p) {
        __half* L = &lds[p & 1][0];
        // ---- A(p): commit staged regs to LDS (compiler inserts vmcnt wait) ----
        #pragma unroll
        for (int r = 0; r < 12; ++r)
            *(uint4*)(L + r * 1088 + lof0) = vm[r];
        if (hwr)
            *(uint4*)(L + rowh * 1088 + lof1) = vh;
        __syncthreads();                               // B(p)

        // ---- issue loads for p+1 (latency hidden under compute below) ----
        if (p < 3) {
            #pragma unroll
            for (int r = 0; r < 12; ++r) {
                int tt = t + (r >> 2) - 1;
                int yy = y0 + (r & 3) - 1;
                bool rok = ((unsigned)tt < 5u) & ((unsigned)yy < 96u);
                int rbase = (tt * 96 + yy) * 12288 + ((p + 1) << 5);
                uint4 v = {0u, 0u, 0u, 0u};
                if (rok & xok0) v = *(const uint4*)(inp + rbase + glo0);
                vm[r] = v;
            }
            {
                int tt = t + (rowh >> 2) - 1;
                int yy = y0 + (rowh & 3) - 1;
                bool rok = ((unsigned)tt < 5u) & ((unsigned)yy < 96u);
                int rbase = (tt * 96 + yy) * 12288 + ((p + 1) << 5);
                uint4 v = {0u, 0u, 0u, 0u};
                if (rok & hld) v = *(const uint4*)(inp + rbase + glo1);
                vh = v;
            }
        }

        // ---- C(p): 27 taps x (1 L1 weight load + 2 ds_read_b128 + 2 MFMA) ----
        const __half* wp_base = wB + (size_t)p * 13824 + l15 * 32 + ksub * 8;
        #pragma unroll
        for (int kt = 0; kt < 3; ++kt) {
            #pragma unroll
            for (int ky = 0; ky < 3; ++ky) {
                const __half* lrow = L + (kt * 4 + w + ky) * 1088;
                #pragma unroll
                for (int kx = 0; kx < 3; ++kx) {
                    int tap = (kt * 3 + ky) * 3 + kx;
                    f16x8 aw = *(const f16x8*)(wp_base + tap * 512);
                    f16x8 b0 = *(const f16x8*)(lrow + offA[kx]);
                    acc0 = __builtin_amdgcn_mfma_f32_16x16x32_f16(aw, b0, acc0, 0, 0, 0);
                    f16x8 b1 = *(const f16x8*)(lrow + offA[kx] + 512);
                    acc1 = __builtin_amdgcn_mfma_f32_16x16x32_f16(aw, b1, acc1, 0, 0, 0);
                }
            }
        }
    }

    // ---- epilogue: D[row=zo=(ksub*4+r)][col=x=l15]; lane-contiguous 64B stores ----
    int yw = y0 + w;
    #pragma unroll
    for (int r = 0; r < 4; ++r) {
        int zo = ksub * 4 + r;
        float bz = bR[zo];
        size_t o = (((size_t)t * 16 + zo) * 96 + yw) * 96 + xseg + l15;
        fld[o]      = acc0[r] + bz;
        fld[o + 16] = acc1[r] + bz;
    }
}

// cellp[t][z][y][x]: 4 half2 of (lo, hi-lo) along x for the 4 (z,y) corner rows.
__global__ __launch_bounds__(256) void pack_kernel(
        const float* __restrict__ fld, Cell* __restrict__ cellp) {
    int i = blockIdx.x * 256 + threadIdx.x;
    if (i >= 737280) return;
    int x = i % 96;
    int r = i / 96;
    int y = r % 96;
    int r2 = r / 96;
    int z = r2 % 16;
    int t = r2 / 16;
    const float* ft = fld + (size_t)t * 147456;
    int xp = min(x + 1, 95);
    int yr0 = y * 96, yr1 = min(y + 1, 95) * 96;
    int zr0 = z * 9216, zr1 = min(z + 1, 15) * 9216;
    float c000 = ft[zr0 + yr0 + x], c001 = ft[zr0 + yr0 + xp];
    float c010 = ft[zr0 + yr1 + x], c011 = ft[zr0 + yr1 + xp];
    float c100 = ft[zr1 + yr0 + x], c101 = ft[zr1 + yr0 + xp];
    float c110 = ft[zr1 + yr1 + x], c111 = ft[zr1 + yr1 + xp];
    Cell cl;
    cl.h0 = __floats2half2_rn(c000, c001 - c000);
    cl.h1 = __floats2half2_rn(c010, c011 - c010);
    cl.h2 = __floats2half2_rn(c100, c101 - c100);
    cl.h3 = __floats2half2_rn(c110, c111 - c110);
    cellp[i] = cl;
}

// 4 lanes per ray, 32 samples each. Grid-space march; log2-domain optics.
// 1-iteration cell prefetch: sample k+1's 16B load issues before sample k's optics,
// so the load->use distance is one full VALU chain (latency hidden, branchless).
__global__ __launch_bounds__(256) void render_kernel(
        const float* __restrict__ ro, const float* __restrict__ rd,
        const Cell* __restrict__ cellp,
        const float* __restrict__ nearA, const float* __restrict__ farA,
        const unsigned* __restrict__ loU, const unsigned* __restrict__ hiU,
        const float* __restrict__ dens_b, float* __restrict__ out) {
    int b = blockIdx.x;                 // 0..2559
    int b7 = b & 7, bhi = b >> 3;
    int t, seg;
    if (b7 < 5) { t = b7; seg = bhi; }
    else { int j = (b7 - 5) * 320 + bhi; t = j / 192; seg = 320 + j % 192; }
    int c = threadIdx.x & 3;
    int ray = t * NRAYS + seg * 64 + (threadIdx.x >> 2);

    const float* o = ro + (size_t)ray * 3;
    const float* d = rd + (size_t)ray * 3;
    float ox = o[0], oy = o[1], oz = o[2];
    float dx = d[0], dy = d[1], dz = d[2];
    float nr = nearA[ray], fr = farA[ray];
    const Cell* vt = cellp + (size_t)t * 147456;
    const float L2E = 1.4426950408889634f;
    float db2 = dens_b[0] * L2E;

    float step = (fr - nr) * 0.0078125f;
    float s  = fmaf((float)(c * 32), step, nr);
    float mid = s + 0.5f * step;
    float pxg = fmaf(dx, mid, ox) * 95.f;
    float pyg = fmaf(dy, mid, oy) * 95.f;
    float pzg = fmaf(dz, mid, oz) * 15.f;
    float ddxg = dx * step * 95.f, ddyg = dy * step * 95.f, ddzg = dz * step * 15.f;

    // prime the pipeline: sample 0's cell + fracs
    float gx = fminf(fmaxf(pxg, 0.f), 95.f);
    float gy = fminf(fmaxf(pyg, 0.f), 95.f);
    float gz = fminf(fmaxf(pzg, 0.f), 15.f);
    int x0 = min((int)gx, 94), y0 = min((int)gy, 94), z0 = min((int)gz, 14);
    float fx = gx - (float)x0, fy = gy - (float)y0, fz = gz - (float)z0;
    Cell cl = vt[z0 * 9216 + y0 * 96 + x0];

    float num = 0.f, den = 0.f, A2 = 0.f;
    float trans = 1.f;
    for (int kk = 0; kk < 32; ++kk) {
        // consume current sample's state
        Cell cc = cl;
        float cfx = fx, cfy = fy, cfz = fz;

        // advance & prefetch next sample's cell (extra tail load is clamped + harmless)
        pxg += ddxg; pyg += ddyg; pzg += ddzg;
        gx = fminf(fmaxf(pxg, 0.f), 95.f);
        gy = fminf(fmaxf(pyg, 0.f), 95.f);
        gz = fminf(fmaxf(pzg, 0.f), 15.f);
        x0 = min((int)gx, 94); y0 = min((int)gy, 94); z0 = min((int)gz, 14);
        fx = gx - (float)x0; fy = gy - (float)y0; fz = gz - (float)z0;
        cl = vt[z0 * 9216 + y0 * 96 + x0];

        // optics on current sample ((lo, hi-lo) packed cells -> v_fma_mix)
        float v00 = fmaf(cfx, __half2float(__high2half(cc.h0)), __half2float(__low2half(cc.h0)));
        float v01 = fmaf(cfx, __half2float(__high2half(cc.h1)), __half2float(__low2half(cc.h1)));
        float v10 = fmaf(cfx, __half2float(__high2half(cc.h2)), __half2float(__low2half(cc.h2)));
        float v11 = fmaf(cfx, __half2float(__high2half(cc.h3)), __half2float(__low2half(cc.h3)));
        float v0  = fmaf(cfy, v01 - v00, v00);
        float v1  = fmaf(cfy, v11 - v10, v10);
        float pre2 = fmaf(fmaf(cfz, v1 - v0, v0), L2E, db2);     // (pre+db)*log2e

        float u = fexp2(-fabsf(pre2));
        float dens2 = fmaxf(pre2, 0.f) + flog2(1.f + u);         // softplus * log2e
        float dd2 = dens2 * step;                                 // dd * log2e
        float ex = fexp2(-dd2);                                   // exp(-dd)
        float wgt = (1.f - ex) * trans;
        num = fmaf(wgt, s, num);
        den += wgt;
        trans *= ex;
        A2 += dd2;
        s += step;
    }
    int lane = threadIdx.x & 63;
    int q = lane & ~3;
    float A0 = __shfl(A2, q,     64);
    float A1 = __shfl(A2, q + 1, 64);
    float Ab = __shfl(A2, q + 2, 64);
    float P = 0.f;
    if (c > 0) P += A0;
    if (c > 1) P += A1;
    if (c > 2) P += Ab;
    float sc = fexp2(-P);
    float numc = num * sc;
    float denc = den * sc;
    numc += __shfl_xor(numc, 1, 64);
    numc += __shfl_xor(numc, 2, 64);
    denc += __shfl_xor(denc, 1, 64);
    denc += __shfl_xor(denc, 2, 64);
    if (c == 0) {
        float depth = numc / (denc + 1e-10f);
        float lo = __uint_as_float(loU[t]);
        float hi = __uint_as_float(hiU[t]);
        depth = fminf(fmaxf(depth, lo), hi);
        out[ray] = depth;
    }
}

extern "C" void kernel_launch(void* const* d_in, const int* in_sizes, int n_in,
                              void* d_out, int out_size, void* d_ws, size_t ws_size,
                              hipStream_t stream) {
    const float* vol = (const float*)d_in[0];
    const float* ro  = (const float*)d_in[1];
    const float* rd  = (const float*)d_in[2];
    const float* cw  = (const float*)d_in[3];
    const float* cb  = (const float*)d_in[4];
    const float* dw  = (const float*)d_in[5];
    const float* dbp = (const float*)d_in[6];
    float* out = (float*)d_out;

    float* ws      = (float*)d_ws;
    float* fld     = ws;                                    // [0 .. 737,280)
    __half* inp    = (__half*)(ws + 737280);                // 5,898,240 halves
    Cell*  cellp   = (Cell*)(ws + 737280);                  // overlaps dead inp
    __half* wB     = (__half*)(ws + 737280 + 2949120);      // 55,296 halves
    float* bR      = ws + 737280 + 2949120 + 27648;         // 16 (+pad to 32)
    float* nearA   = bR + 32;
    float* farA    = nearA + 163840;
    unsigned* loU  = (unsigned*)(farA + 163840);
    unsigned* hiU  = loU + 8;

    hipLaunchKernelGGL(prep_w_kernel, dim3(216), dim3(256), 0, stream,
                       cw, cb, dw, wB, bR, loU, hiU);
    hipLaunchKernelGGL(transpose_vol_kernel, dim3(480), dim3(256), 0, stream, vol, inp);
    hipLaunchKernelGGL(nearfar_kernel, dim3(640), dim3(256), 0, stream,
                       ro, rd, nearA, farA, loU, hiU);
    hipLaunchKernelGGL(conv_mfma_kernel, dim3(720), dim3(128), 0, stream,
                       inp, wB, bR, fld);
    hipLaunchKernelGGL(pack_kernel, dim3(2880), dim3(256), 0, stream, fld, cellp);
    hipLaunchKernelGGL(render_kernel, dim3(2560), dim3(256), 0, stream,
                       ro, rd, cellp, nearA, farA, loU, hiU, dbp, out);
}

// Round 5
// 165.891 us; speedup vs baseline: 1.2938x; 1.2938x over previous
//
#include <hip/hip_runtime.h>
#include <hip/hip_fp16.h>
#include <cstdint>
#include <cstddef>

#define T_DIM 5
#define F_DIM 8
#define Z_DIM 16
#define Y_DIM 96
#define X_DIM 96
#define NRAYS 32768
#define K_SAMP 128

// Pipeline (4 launches):
//   setup     : fused {transpose -> inp f16 [t][y][x][ci]} + {prep -> wB,bR} + {nearfar}
//   conv_mfma : fld f32 [t][zo][y][x] via v_mfma_f32_16x16x32_f16
//               LDS double-buffer, reg-staged async prefetch, 1 barrier/phase
//   pack      : fld -> cellp, cells stored as (lo, hi-lo) half2 pairs
//   render    : grid-space march, log2 optics, exec-masked cached cell reload,
//               per-ray clamp (global lo/hi reduction eliminated; error ~1e-8)

struct __align__(16) Cell { __half2 h0, h1, h2, h3; };

typedef __attribute__((ext_vector_type(4))) float     f32x4;
typedef __attribute__((ext_vector_type(8))) _Float16  f16x8;

__device__ __forceinline__ float fexp2(float x) { return __builtin_amdgcn_exp2f(x); }   // v_exp_f32
__device__ __forceinline__ float flog2(float x) { return __builtin_amdgcn_logf(x); }    // v_log_f32

// blocks [0,480): transpose | [480,696): weight prep | [696,1336): nearfar
__global__ __launch_bounds__(256) void setup_kernel(
        const float* __restrict__ xin, __half* __restrict__ inp,
        const float* __restrict__ w, const float* __restrict__ cb,
        const float* __restrict__ dw, __half* __restrict__ wB, float* __restrict__ bR,
        const float* __restrict__ ro, const float* __restrict__ rd,
        float* __restrict__ nearA, float* __restrict__ farA) {
    int b = blockIdx.x;
    if (b < 480) {
        // ---- transpose: inp[((t*96+y)*96+x)*128 + f*16+z] = (half) vol[f][t][z][y][x]
        __shared__ __half lds[96 * 136];
        int t = b / 96, y = b - (b / 96) * 96;
        for (int i = threadIdx.x; i < 12288; i += 256) {
            int row = i / 96;
            int x   = i - row * 96;
            int f = row >> 4, z = row & 15;
            float v = xin[(((size_t)(f * 5 + t) * 16 + z) * 96 + y) * 96 + x];
            lds[x * 136 + row] = __float2half(v);
        }
        __syncthreads();
        __half* ob = inp + ((size_t)(t * 96 + y) * 96) * 128;
        for (int c = threadIdx.x; c < 1536; c += 256) {
            int x = c >> 4, sub = c & 15;
            uint4 v = *(const uint4*)(lds + x * 136 + sub * 8);
            *(uint4*)(ob + (size_t)x * 128 + sub * 8) = v;
        }
    } else if (b < 696) {
        // ---- weight prep: wB[((p*27+tap)*16+zo)*32+cs], ci = p*32+cs
        int i = (b - 480) * 256 + threadIdx.x;       // 0 .. 55295 exactly
        if (i < 16) {
            float s = 0.f;
            #pragma unroll
            for (int f = 0; f < 8; ++f) s += cb[f * 16 + i] * dw[f];
            bR[i] = s;
        }
        int cs  = i & 31;
        int zo  = (i >> 5) & 15;
        int pt  = i >> 9;
        int p   = pt / 27;
        int tap = pt - p * 27;
        int ci  = p * 32 + cs;
        float s = 0.f;
        #pragma unroll
        for (int f = 0; f < 8; ++f)
            s += w[(size_t)((f * 16 + zo) * 128 + ci) * 27 + tap] * dw[f];
        wB[i] = __float2half(s);
    } else {
        // ---- nearfar: per-ray near/far only (no global reduction needed anymore)
        int gid = (b - 696) * 256 + threadIdx.x;     // 0 .. 163839
        const float* o = ro + (size_t)gid * 3;
        const float* d = rd + (size_t)gid * 3;
        float ox = o[0], oy = o[1], oz = o[2];
        float dx = d[0], dy = d[1], dz = d[2];
        float t1x = (0.f - ox) / dx, t2x = (1.f - ox) / dx;
        float t1y = (0.f - oy) / dy, t2y = (1.f - oy) / dy;
        float t1z = (0.f - oz) / dz, t2z = (1.f - oz) / dz;
        float nr = fmaxf(fmaxf(fminf(t1x, t2x), fminf(t1y, t2y)), fminf(t1z, t2z));
        float fr = fminf(fminf(fmaxf(t1x, t2x), fmaxf(t1y, t2y)), fmaxf(t1z, t2z));
        nr = fmaxf(nr, 0.01f);
        fr = fmaxf(fr, nr + 1e-6f);
        nearA[gid] = nr;
        farA[gid]  = fr;
    }
}

// Block = (t, y-pair, 32-x seg), 128 thr (2 waves; wave w -> y = y0+w, two 16-x tiles).
// LDS: 2 buffers of [12 rows][34 x][4 slots of 8 halves], slot s' = sub ^ ((xl>>1)&3).
// Phase p: ds_write(buf[p&1]) -> barrier -> issue global loads(p+1) -> compute(buf[p&1]).
// Buffer safety: per-wave order C(p-1) < A(p) < B(p); so at barrier B(p) every wave has
// finished reading buf[(p+1)&1]; A(p+1) writes it only after B(p). One barrier per phase.
__global__ __launch_bounds__(128) void conv_mfma_kernel(
        const __half* __restrict__ inp, const __half* __restrict__ wB,
        const float* __restrict__ bR, float* __restrict__ fld) {
    int bid = blockIdx.x;
    int wg  = (bid & 7) * 90 + (bid >> 3);     // bijective XCD swizzle (720 = 8*90)
    int xs  = wg % 3;
    int rem = wg / 3;
    int yp  = rem % 48;
    int t   = rem / 48;
    int xseg = xs * 32, y0 = yp * 2;

    __shared__ __half lds[2][12 * 34 * 32];          // 2 x 26,112 B
    const int w    = threadIdx.x >> 6;
    const int lane = threadIdx.x & 63;
    const int l15  = lane & 15;
    const int ksub = lane >> 4;

    // ---- main staging columns: 128 lanes x 12 rows (xl 0..31, sub 0..3) ----
    const int xl0 = threadIdx.x >> 2, sub0 = threadIdx.x & 3;
    const int xg0 = xseg + xl0 - 1;
    const bool xok0 = (unsigned)xg0 < 96u;
    const int glo0 = xg0 * 128 + sub0 * 8;                       // halves (+p*32 later)
    const int lof0 = xl0 * 32 + ((sub0 ^ ((xl0 >> 1) & 3)) << 3);
    // ---- halo: 96 chunks (xl 32..33, sub 0..3, rows 0..11) -> lanes 0..95, 1 each ----
    const int q    = threadIdx.x / 12;                           // 0..10
    const int rowh = threadIdx.x - q * 12;                       // 0..11
    const int xl1  = 32 + (q >> 2), sub1 = q & 3;
    const int xg1  = xseg + xl1 - 1;
    const bool hwr = (q < 8);
    const bool hld = hwr && ((unsigned)xg1 < 96u);
    const int glo1 = xg1 * 128 + sub1 * 8;
    const int lof1 = xl1 * 32 + ((sub1 ^ ((xl1 >> 1) & 3)) << 3);

    // ---- swizzled B-fragment read offsets (halves) ----
    int offA[3];
    #pragma unroll
    for (int kx = 0; kx < 3; ++kx) {
        int X = l15 + kx;
        offA[kx] = X * 32 + ((ksub ^ ((X >> 1) & 3)) << 3);      // tile B = +512
    }

    uint4 vm[12];
    uint4 vh;
    f32x4 acc0 = {0.f, 0.f, 0.f, 0.f};
    f32x4 acc1 = {0.f, 0.f, 0.f, 0.f};

    // ---- prologue: issue loads for p=0 ----
    #pragma unroll
    for (int r = 0; r < 12; ++r) {
        int tt = t + (r >> 2) - 1;
        int yy = y0 + (r & 3) - 1;
        bool rok = ((unsigned)tt < 5u) & ((unsigned)yy < 96u);
        int rbase = (tt * 96 + yy) * 12288;
        uint4 v = {0u, 0u, 0u, 0u};
        if (rok & xok0) v = *(const uint4*)(inp + rbase + glo0);
        vm[r] = v;
    }
    {
        int tt = t + (rowh >> 2) - 1;
        int yy = y0 + (rowh & 3) - 1;
        bool rok = ((unsigned)tt < 5u) & ((unsigned)yy < 96u);
        int rbase = (tt * 96 + yy) * 12288;
        uint4 v = {0u, 0u, 0u, 0u};
        if (rok & hld) v = *(const uint4*)(inp + rbase + glo1);
        vh = v;
    }

    #pragma unroll
    for (int p = 0; p < 4; ++p) {
        __half* L = &lds[p & 1][0];
        // ---- A(p): commit staged regs to LDS ----
        #pragma unroll
        for (int r = 0; r < 12; ++r)
            *(uint4*)(L + r * 1088 + lof0) = vm[r];
        if (hwr)
            *(uint4*)(L + rowh * 1088 + lof1) = vh;
        __syncthreads();                               // B(p)

        // ---- issue loads for p+1 (hidden under compute below) ----
        if (p < 3) {
            #pragma unroll
            for (int r = 0; r < 12; ++r) {
                int tt = t + (r >> 2) - 1;
                int yy = y0 + (r & 3) - 1;
                bool rok = ((unsigned)tt < 5u) & ((unsigned)yy < 96u);
                int rbase = (tt * 96 + yy) * 12288 + ((p + 1) << 5);
                uint4 v = {0u, 0u, 0u, 0u};
                if (rok & xok0) v = *(const uint4*)(inp + rbase + glo0);
                vm[r] = v;
            }
            {
                int tt = t + (rowh >> 2) - 1;
                int yy = y0 + (rowh & 3) - 1;
                bool rok = ((unsigned)tt < 5u) & ((unsigned)yy < 96u);
                int rbase = (tt * 96 + yy) * 12288 + ((p + 1) << 5);
                uint4 v = {0u, 0u, 0u, 0u};
                if (rok & hld) v = *(const uint4*)(inp + rbase + glo1);
                vh = v;
            }
        }

        // ---- C(p): 27 taps x (1 L1 weight load + 2 ds_read_b128 + 2 MFMA) ----
        const __half* wp_base = wB + (size_t)p * 13824 + l15 * 32 + ksub * 8;
        #pragma unroll
        for (int kt = 0; kt < 3; ++kt) {
            #pragma unroll
            for (int ky = 0; ky < 3; ++ky) {
                const __half* lrow = L + (kt * 4 + w + ky) * 1088;
                #pragma unroll
                for (int kx = 0; kx < 3; ++kx) {
                    int tap = (kt * 3 + ky) * 3 + kx;
                    f16x8 aw = *(const f16x8*)(wp_base + tap * 512);
                    f16x8 b0 = *(const f16x8*)(lrow + offA[kx]);
                    acc0 = __builtin_amdgcn_mfma_f32_16x16x32_f16(aw, b0, acc0, 0, 0, 0);
                    f16x8 b1 = *(const f16x8*)(lrow + offA[kx] + 512);
                    acc1 = __builtin_amdgcn_mfma_f32_16x16x32_f16(aw, b1, acc1, 0, 0, 0);
                }
            }
        }
    }

    // ---- epilogue: D[row=zo=(ksub*4+r)][col=x=l15]; lane-contiguous 64B stores ----
    int yw = y0 + w;
    #pragma unroll
    for (int r = 0; r < 4; ++r) {
        int zo = ksub * 4 + r;
        float bz = bR[zo];
        size_t o = (((size_t)t * 16 + zo) * 96 + yw) * 96 + xseg + l15;
        fld[o]      = acc0[r] + bz;
        fld[o + 16] = acc1[r] + bz;
    }
}

// cellp[t][z][y][x]: 4 half2 of (lo, hi-lo) along x for the 4 (z,y) corner rows.
__global__ __launch_bounds__(256) void pack_kernel(
        const float* __restrict__ fld, Cell* __restrict__ cellp) {
    int i = blockIdx.x * 256 + threadIdx.x;
    if (i >= 737280) return;
    int x = i % 96;
    int r = i / 96;
    int y = r % 96;
    int r2 = r / 96;
    int z = r2 % 16;
    int t = r2 / 16;
    const float* ft = fld + (size_t)t * 147456;
    int xp = min(x + 1, 95);
    int yr0 = y * 96, yr1 = min(y + 1, 95) * 96;
    int zr0 = z * 9216, zr1 = min(z + 1, 15) * 9216;
    float c000 = ft[zr0 + yr0 + x], c001 = ft[zr0 + yr0 + xp];
    float c010 = ft[zr0 + yr1 + x], c011 = ft[zr0 + yr1 + xp];
    float c100 = ft[zr1 + yr0 + x], c101 = ft[zr1 + yr0 + xp];
    float c110 = ft[zr1 + yr1 + x], c111 = ft[zr1 + yr1 + xp];
    Cell cl;
    cl.h0 = __floats2half2_rn(c000, c001 - c000);
    cl.h1 = __floats2half2_rn(c010, c011 - c010);
    cl.h2 = __floats2half2_rn(c100, c101 - c100);
    cl.h3 = __floats2half2_rn(c110, c111 - c110);
    cellp[i] = cl;
}

// 4 lanes per ray, 32 samples each. Grid-space march; log2-domain optics.
// Cell load is exec-masked behind an index-change test (proven fastest structure:
// scattered-gather throughput is the limiter, so minimize issued gathers).
__global__ __launch_bounds__(256) void render_kernel(
        const float* __restrict__ ro, const float* __restrict__ rd,
        const Cell* __restrict__ cellp,
        const float* __restrict__ nearA, const float* __restrict__ farA,
        const float* __restrict__ dens_b, float* __restrict__ out) {
    int b = blockIdx.x;                 // 0..2559
    int b7 = b & 7, bhi = b >> 3;
    int t, seg;
    if (b7 < 5) { t = b7; seg = bhi; }
    else { int j = (b7 - 5) * 320 + bhi; t = j / 192; seg = 320 + j % 192; }
    int c = threadIdx.x & 3;
    int ray = t * NRAYS + seg * 64 + (threadIdx.x >> 2);

    const float* o = ro + (size_t)ray * 3;
    const float* d = rd + (size_t)ray * 3;
    float ox = o[0], oy = o[1], oz = o[2];
    float dx = d[0], dy = d[1], dz = d[2];
    float nr = nearA[ray], fr = farA[ray];
    const Cell* vt = cellp + (size_t)t * 147456;
    const float L2E = 1.4426950408889634f;
    float db2 = dens_b[0] * L2E;

    float span = fr - nr;
    float step = span * 0.0078125f;
    float s  = fmaf((float)(c * 32), step, nr);
    float mid = s + 0.5f * step;
    float pxg = fmaf(dx, mid, ox) * 95.f;
    float pyg = fmaf(dy, mid, oy) * 95.f;
    float pzg = fmaf(dz, mid, oz) * 15.f;
    float ddxg = dx * step * 95.f, ddyg = dy * step * 95.f, ddzg = dz * step * 15.f;

    float num = 0.f, den = 0.f, A2 = 0.f;
    float trans = 1.f;
    int pidx = -1;
    Cell cl;
    for (int kk = 0; kk < 32; ++kk) {
        float gx = fminf(fmaxf(pxg, 0.f), 95.f);     // v_med3
        float gy = fminf(fmaxf(pyg, 0.f), 95.f);
        float gz = fminf(fmaxf(pzg, 0.f), 15.f);
        int x0 = min((int)gx, 94), y0 = min((int)gy, 94), z0 = min((int)gz, 14);
        float fx = gx - (float)x0, fy = gy - (float)y0, fz = gz - (float)z0;

        int idx = z0 * 9216 + y0 * 96 + x0;
        if (idx != pidx) {                 // exec-masked 16B gather, only changed lanes
            pidx = idx;
            cl = vt[idx];
        }

        // (lo, hi-lo) packed cells -> v_fma_mix lerps
        float v00 = fmaf(fx, __half2float(__high2half(cl.h0)), __half2float(__low2half(cl.h0)));
        float v01 = fmaf(fx, __half2float(__high2half(cl.h1)), __half2float(__low2half(cl.h1)));
        float v10 = fmaf(fx, __half2float(__high2half(cl.h2)), __half2float(__low2half(cl.h2)));
        float v11 = fmaf(fx, __half2float(__high2half(cl.h3)), __half2float(__low2half(cl.h3)));
        float v0  = fmaf(fy, v01 - v00, v00);
        float v1  = fmaf(fy, v11 - v10, v10);
        float pre2 = fmaf(fmaf(fz, v1 - v0, v0), L2E, db2);      // (pre+db)*log2e

        float u = fexp2(-fabsf(pre2));
        float dens2 = fmaxf(pre2, 0.f) + flog2(1.f + u);         // softplus * log2e
        float dd2 = dens2 * step;                                 // dd * log2e
        float ex = fexp2(-dd2);                                   // exp(-dd)
        float wgt = (1.f - ex) * trans;
        num = fmaf(wgt, s, num);
        den += wgt;
        trans *= ex;
        A2 += dd2;
        s += step; pxg += ddxg; pyg += ddyg; pzg += ddzg;
    }
    int lane = threadIdx.x & 63;
    int qb = lane & ~3;
    float A0 = __shfl(A2, qb,     64);
    float A1 = __shfl(A2, qb + 1, 64);
    float Ab = __shfl(A2, qb + 2, 64);
    float P = 0.f;
    if (c > 0) P += A0;
    if (c > 1) P += A1;
    if (c > 2) P += Ab;
    float sc = fexp2(-P);
    float numc = num * sc;
    float denc = den * sc;
    numc += __shfl_xor(numc, 1, 64);
    numc += __shfl_xor(numc, 2, 64);
    denc += __shfl_xor(denc, 1, 64);
    denc += __shfl_xor(denc, 2, 64);
    if (c == 0) {
        float depth = numc / (denc + 1e-10f);
        // per-ray clamp [near, s_last]; equals ref's global clamp to ~1e-8 (see header)
        float slast = fmaf(0.9921875f, span, nr);
        depth = fminf(fmaxf(depth, nr), slast);
        out[ray] = depth;
    }
}

extern "C" void kernel_launch(void* const* d_in, const int* in_sizes, int n_in,
                              void* d_out, int out_size, void* d_ws, size_t ws_size,
                              hipStream_t stream) {
    const float* vol = (const float*)d_in[0];
    const float* ro  = (const float*)d_in[1];
    const float* rd  = (const float*)d_in[2];
    const float* cw  = (const float*)d_in[3];
    const float* cb  = (const float*)d_in[4];
    const float* dw  = (const float*)d_in[5];
    const float* dbp = (const float*)d_in[6];
    float* out = (float*)d_out;

    float* ws      = (float*)d_ws;
    float* fld     = ws;                                    // [0 .. 737,280)
    __half* inp    = (__half*)(ws + 737280);                // 5,898,240 halves
    Cell*  cellp   = (Cell*)(ws + 737280);                  // overlaps dead inp
    __half* wB     = (__half*)(ws + 737280 + 2949120);      // 55,296 halves
    float* bR      = ws + 737280 + 2949120 + 27648;         // 16 (+pad to 32)
    float* nearA   = bR + 32;
    float* farA    = nearA + 163840;

    hipLaunchKernelGGL(setup_kernel, dim3(1336), dim3(256), 0, stream,
                       vol, inp, cw, cb, dw, wB, bR, ro, rd, nearA, farA);
    hipLaunchKernelGGL(conv_mfma_kernel, dim3(720), dim3(128), 0, stream,
                       inp, wB, bR, fld);
    hipLaunchKernelGGL(pack_kernel, dim3(2880), dim3(256), 0, stream, fld, cellp);
    hipLaunchKernelGGL(render_kernel, dim3(2560), dim3(256), 0, stream,
                       ro, rd, cellp, nearA, farA, dbp, out);
}